// Round 3
// baseline (261.665 us; speedup 1.0000x reference)
//
#include <hip/hip_runtime.h>
#include <stdint.h>

// Problem: B=16, C=64, H=128, W=128, HX=HY=64. ALL I/O is float32 (per reference).
// Pass X: 2048 seqs (b,h), T=128 (w).  Pass Y: 2048 seqs (b,w), T=128 (h).
// d_out (fp32, 67MB) serially reused: out_x staging -> final output.
// d_ws: pre (fp32, 67,108,864 B).

#define TLEN 128

typedef __bf16 bf16x8 __attribute__((ext_vector_type(8)));
typedef float  f32x4  __attribute__((ext_vector_type(4)));
typedef unsigned short u16x4 __attribute__((ext_vector_type(4)));

static __device__ __forceinline__ float bf2f(unsigned short s){
    union { unsigned int u; float f; } v; v.u = ((unsigned int)s) << 16; return v.f;
}
static __device__ __forceinline__ unsigned short f2bf(float f){
    union { float f; unsigned int u; } v; v.f = f;
    return (unsigned short)((v.u + 0x7FFFu + ((v.u >> 16) & 1u)) >> 16);
}
static __device__ __forceinline__ __bf16 us2b(unsigned short s){
    union { unsigned short u; __bf16 b; } v; v.u = s; return v.b;
}
struct bfpair { __bf16 hi, lo; };
static __device__ __forceinline__ bfpair splitf(float f){
    unsigned short h = f2bf(f);
    bfpair r;
    r.hi = us2b(h);
    r.lo = us2b(f2bf(f - bf2f(h)));
    return r;
}
static __device__ __forceinline__ float fast_tanh(float x){
    // tanh(x) = 1 - 2/(exp(2x)+1), exp(2x)=exp2(2*log2(e)*x). Saturates correctly.
    float e = __builtin_amdgcn_exp2f(x * 2.8853900817779268f);
    return 1.0f - 2.0f * __builtin_amdgcn_rcpf(e + 1.0f);
}

// ---------------------------------------------------------------------------
// Projection: pre[r][j] = sum_k A_row(r)[k] * Wih[j][k] + bih[j] + bhh[j]
// fp32 inputs; hi/lo bf16 split, 3-term MFMA (error ~2^-17 rel).
// PASS 0: A = x in NCHW, row r=(b*16384+hw), k=c -> A[b*2^20 + k*16384 + hw]
// PASS 1: A = out_x fp32 [ (b*128+h)*128+w ][k], GEMM row r=(b*128+w)*128+h
// Block 256 thr / 4 waves; wave covers 32 rows (2 m-tiles) x all 64 j.
template<int PASS>
__global__ __launch_bounds__(256) void k_proj(const float* __restrict__ A,
                                              const float* __restrict__ Wih,
                                              const float* __restrict__ b1,
                                              const float* __restrict__ b2,
                                              float* __restrict__ pre){
    int lane = threadIdx.x & 63;
    int wv   = threadIdx.x >> 6;
    int q    = lane >> 4, l15 = lane & 15;

    // Weight fragments: B[n=l15][k=q*8+i] per 16-col tile n; j = n*16+l15
    bf16x8 Whi[4][2], Wlo[4][2];
#pragma unroll
    for (int n = 0; n < 4; n++)
#pragma unroll
        for (int kc = 0; kc < 2; kc++){
            const float* p = Wih + (n * 16 + l15) * 64 + kc * 32 + q * 8;
#pragma unroll
            for (int i = 0; i < 8; i++){
                bfpair s = splitf(p[i]);
                Whi[n][kc][i] = s.hi;
                Wlo[n][kc][i] = s.lo;
            }
        }
    float bias[4];
#pragma unroll
    for (int n = 0; n < 4; n++){
        int j = n * 16 + l15;
        bias[n] = b1[j] + b2[j];
    }

    int row0 = blockIdx.x * 128 + wv * 32;
#pragma unroll
    for (int mi = 0; mi < 2; mi++){
        int rb = row0 + mi * 16;
        int r  = rb + l15;           // A-fragment: m = l15
        float av[2][8];
        if constexpr (PASS == 0){
            int b = r >> 14, hw = r & 16383;
            const float* xb = A + (size_t)b * 1048576 + hw;
#pragma unroll
            for (int kc = 0; kc < 2; kc++)
#pragma unroll
                for (int i = 0; i < 8; i++)
                    av[kc][i] = xb[(size_t)(kc * 32 + q * 8 + i) * 16384];
        } else {
            int b = r >> 14, w = (r >> 7) & 127, h = r & 127;
            const float* xb = A + ((size_t)((b * 128 + h) * 128 + w)) * 64;
#pragma unroll
            for (int kc = 0; kc < 2; kc++){
                f32x4 v0 = *(const f32x4*)(xb + kc * 32 + q * 8);
                f32x4 v1 = *(const f32x4*)(xb + kc * 32 + q * 8 + 4);
#pragma unroll
                for (int i = 0; i < 4; i++){ av[kc][i] = v0[i]; av[kc][4 + i] = v1[i]; }
            }
        }
        bf16x8 Ahi[2], Alo[2];
#pragma unroll
        for (int kc = 0; kc < 2; kc++)
#pragma unroll
            for (int i = 0; i < 8; i++){
                bfpair s = splitf(av[kc][i]);
                Ahi[kc][i] = s.hi;
                Alo[kc][i] = s.lo;
            }

        f32x4 acc[4];
#pragma unroll
        for (int n = 0; n < 4; n++) acc[n] = (f32x4){bias[n], bias[n], bias[n], bias[n]};
#pragma unroll
        for (int n = 0; n < 4; n++)
#pragma unroll
            for (int kc = 0; kc < 2; kc++){
                acc[n] = __builtin_amdgcn_mfma_f32_16x16x32_bf16(Ahi[kc], Whi[n][kc], acc[n], 0, 0, 0);
                acc[n] = __builtin_amdgcn_mfma_f32_16x16x32_bf16(Alo[kc], Whi[n][kc], acc[n], 0, 0, 0);
                acc[n] = __builtin_amdgcn_mfma_f32_16x16x32_bf16(Ahi[kc], Wlo[n][kc], acc[n], 0, 0, 0);
            }
        // C layout: col = n*16+l15, row = rb + q*4 + rr
#pragma unroll
        for (int n = 0; n < 4; n++)
#pragma unroll
            for (int rr = 0; rr < 4; rr++)
                pre[(size_t)(rb + q * 4 + rr) * 64 + n * 16 + l15] = acc[n][rr];
    }
}

// ---------------------------------------------------------------------------
// Scan: h_t = tanh(pre_t + Whh h_{t-1}). 128 blocks x 256 thr (4 waves).
// Block = 16 sequences; wave wv owns the 16-row j-tile mt=wv.
// Orientation D[m=j_out][n=seq] = Whh * H^T: Whh (hi/lo split) pinned in VGPRs.
// h round-trips through LDS as split bf16 pair each step (parity dbuf).
// PASS 0: out_x[(n0+seq)*T + t][j] fp32.   PASS 1: out[b][j][t][w] fp32.
template<int PASS>
__global__ __launch_bounds__(256) void k_scan(const float* __restrict__ pre,
                                              const float* __restrict__ Whh,
                                              float* __restrict__ out){
    __shared__ alignas(16) unsigned short hbuf[2][16][2][72]; // [par][seq][hi/lo][j(+pad)]
    int lane = threadIdx.x & 63;
    int wv   = threadIdx.x >> 6;      // = mt (j-tile)
    int q = lane >> 4, l15 = lane & 15;
    int n0 = blockIdx.x * 16;

    // A-frags: m = j_out = wv*16+l15, k = j_in = kc*32+q*8+i
    bf16x8 Ahi[2], Alo[2];
#pragma unroll
    for (int kc = 0; kc < 2; kc++){
        const float* p = Whh + (wv * 16 + l15) * 64 + kc * 32 + q * 8;
#pragma unroll
        for (int i = 0; i < 8; i++){
            bfpair s = splitf(p[i]);
            Ahi[kc][i] = s.hi;
            Alo[kc][i] = s.lo;
        }
    }
    bf16x8 Bhi[2], Blo[2];
#pragma unroll
    for (int kc = 0; kc < 2; kc++)
#pragma unroll
        for (int i = 0; i < 8; i++){ Bhi[kc][i] = us2b(0); Blo[kc][i] = us2b(0); }

    int bb = n0 >> 7, w0 = n0 & 127;   // PASS 1 output addressing

    const float* prow = pre + (size_t)(n0 + l15) * TLEN * 64 + wv * 16 + q * 4;
    f32x4 cur = *(const f32x4*)prow;   // t = 0

    for (int t = 0; t < TLEN; t++){
        f32x4 nxt = (f32x4){0.f, 0.f, 0.f, 0.f};
        if (t < TLEN - 1) nxt = *(const f32x4*)(prow + (size_t)(t + 1) * 64);

        f32x4 acc = cur;
#pragma unroll
        for (int kc = 0; kc < 2; kc++){
            acc = __builtin_amdgcn_mfma_f32_16x16x32_bf16(Ahi[kc], Bhi[kc], acc, 0, 0, 0);
            acc = __builtin_amdgcn_mfma_f32_16x16x32_bf16(Ahi[kc], Blo[kc], acc, 0, 0, 0);
            acc = __builtin_amdgcn_mfma_f32_16x16x32_bf16(Alo[kc], Bhi[kc], acc, 0, 0, 0);
        }
        int par = t & 1;
        int j0  = wv * 16 + q * 4;     // rows of this lane's acc
        float tv[4];
        u16x4 hi4, lo4;
#pragma unroll
        for (int r = 0; r < 4; r++){
            tv[r] = fast_tanh(acc[r]);
            unsigned short h = f2bf(tv[r]);
            hi4[r] = h;
            lo4[r] = f2bf(tv[r] - bf2f(h));
        }
        // acc lane mapping: n(seq) = l15, m(j) = j0 + r
        *(u16x4*)&hbuf[par][l15][0][j0] = hi4;
        *(u16x4*)&hbuf[par][l15][1][j0] = lo4;

        if constexpr (PASS == 0){
            f32x4 ov = (f32x4){tv[0], tv[1], tv[2], tv[3]};
            *(f32x4*)(out + ((size_t)(n0 + l15) * TLEN + t) * 64 + j0) = ov;
        } else {
#pragma unroll
            for (int r = 0; r < 4; r++)
                out[((size_t)(bb * 64 + j0 + r) * TLEN + t) * 128 + w0 + l15] = tv[r];
        }
        __syncthreads();
        // B-frags for next step: n = l15, k = kc*32+q*8+i
#pragma unroll
        for (int kc = 0; kc < 2; kc++){
            Bhi[kc] = *(const bf16x8*)&hbuf[par][l15][0][kc * 32 + q * 8];
            Blo[kc] = *(const bf16x8*)&hbuf[par][l15][1][kc * 32 + q * 8];
        }
        cur = nxt;
    }
}

// ---------------------------------------------------------------------------
extern "C" void kernel_launch(void* const* d_in, const int* in_sizes, int n_in,
                              void* d_out, int out_size, void* d_ws, size_t ws_size,
                              hipStream_t stream){
    (void)in_sizes; (void)n_in; (void)out_size; (void)ws_size;
    const float* x    = (const float*)d_in[0];
    const float* Wihx = (const float*)d_in[1];
    const float* Whhx = (const float*)d_in[2];
    const float* bihx = (const float*)d_in[3];
    const float* bhhx = (const float*)d_in[4];
    const float* Wihy = (const float*)d_in[5];
    const float* Whhy = (const float*)d_in[6];
    const float* bihy = (const float*)d_in[7];
    const float* bhhy = (const float*)d_in[8];
    float* ob  = (float*)d_out;   // out_x staging, then final output
    float* pre = (float*)d_ws;    // 67,108,864 B

    k_proj<0><<<2048, 256, 0, stream>>>(x,  Wihx, bihx, bhhx, pre);
    k_scan<0><<<128,  256, 0, stream>>>(pre, Whhx, ob);         // out_x fp32
    k_proj<1><<<2048, 256, 0, stream>>>(ob, Wihy, bihy, bhhy, pre);
    k_scan<1><<<128,  256, 0, stream>>>(pre, Whhy, ob);         // final fp32
}